// Round 2
// baseline (3727.126 us; speedup 1.0000x reference)
//
#include <hip/hip_runtime.h>
#include <hip/hip_bf16.h>
#include <math.h>

#define H 1024
#define L_ENC 128
#define V 50257
#define STEPS 32
#define STOP_ID 658

// workspace layout (float offsets)
#define WS_H     0        // 1024  hidden state h
#define WS_HNEW  1024     // 1024  candidate h_new
#define WS_GH    2048     // 3072  gh = h @ whh.T + bhh
#define WS_X     5120     // 1024  x = relu(comb)
#define WS_PMAX  6144     // 629   per-block argmax value
#define WS_PIDX  6784     // 629   per-block argmax index (int)
#define WS_TOK   7424     // int   current token
#define WS_DONE  7425     // int   done flag
#define WS_CNT   7426     // unsigned: last-block counter

#define NB_OUT 629        // 629 blocks * 80 rows = 50320 >= 50257
#define ROWS_PB 80

__global__ __launch_bounds__(1024) void k_init(const int* __restrict__ dec_in,
                                               const float* __restrict__ h0,
                                               float* __restrict__ ws) {
    int t = threadIdx.x;
    ws[WS_H + t] = h0[t];
    if (t == 0) {
        ((int*)(ws + WS_TOK))[0]  = dec_in[0];
        ((int*)(ws + WS_DONE))[0] = 0;
        ((unsigned*)(ws + WS_CNT))[0] = 0;
    }
}

// K_A: blocks 0..63   : redundant attention + softmax + ctx + 16 comb rows
//      blocks 64..831 : gh rows (4/block, one per wave)
__global__ __launch_bounds__(256) void k_A(const float* __restrict__ embedding,
                                           const float* __restrict__ attn_w,
                                           const float* __restrict__ attn_b,
                                           const float* __restrict__ enc,
                                           const float* __restrict__ comb_w,
                                           const float* __restrict__ comb_b,
                                           const float* __restrict__ whh,
                                           const float* __restrict__ bhh,
                                           float* __restrict__ ws) {
    const int t = threadIdx.x, wave = t >> 6, lane = t & 63;
    const int tok = ((const int*)(ws + WS_TOK))[0];
    const float4* h4g = (const float4*)(ws + WS_H);

    if (blockIdx.x >= 64) {
        // ---- gh = h @ whh.T + bhh ----
        const int r = (blockIdx.x - 64) * 4 + wave;     // 0..3071
        const float4* w4 = (const float4*)(whh + (size_t)r * H);
        float4 a[4], b[4];
        #pragma unroll
        for (int m = 0; m < 4; ++m) { a[m] = w4[lane + (m << 6)]; }
        #pragma unroll
        for (int m = 0; m < 4; ++m) { b[m] = h4g[lane + (m << 6)]; }
        float s = 0.f;
        #pragma unroll
        for (int m = 0; m < 4; ++m)
            s += a[m].x * b[m].x + a[m].y * b[m].y + a[m].z * b[m].z + a[m].w * b[m].w;
        #pragma unroll
        for (int o = 32; o; o >>= 1) s += __shfl_down(s, o);
        if (lane == 0) ws[WS_GH + r] = s + bhh[r];
        return;
    }

    // ---- attention (redundant per block) + ctx + comb ----
    __shared__ float s_alog[L_ENC];
    __shared__ __align__(16) float s_eh[2048];   // [emb ; h]
    __shared__ __align__(16) float s_cat[2048];  // [emb ; ctx]
    const float4* e4 = (const float4*)(embedding + (size_t)tok * H);
    float4* eh4  = (float4*)s_eh;
    float4* cat4 = (float4*)s_cat;
    float4 ev = e4[t];
    eh4[t] = ev;
    eh4[256 + t] = h4g[t];
    cat4[t] = ev;
    __syncthreads();

    // 128 attn rows, 32/wave, batch 2
    for (int it = 0; it < 16; ++it) {
        const int r0 = wave * 32 + it * 2;
        const float4* wa = (const float4*)(attn_w + (size_t)r0 * 2048);
        float4 a0[8], a1[8];
        #pragma unroll
        for (int m = 0; m < 8; ++m) a0[m] = wa[lane + (m << 6)];
        #pragma unroll
        for (int m = 0; m < 8; ++m) a1[m] = wa[512 + lane + (m << 6)];
        float s0 = 0.f, s1 = 0.f;
        #pragma unroll
        for (int m = 0; m < 8; ++m) {
            float4 c = eh4[lane + (m << 6)];
            s0 += a0[m].x * c.x + a0[m].y * c.y + a0[m].z * c.z + a0[m].w * c.w;
            s1 += a1[m].x * c.x + a1[m].y * c.y + a1[m].z * c.z + a1[m].w * c.w;
        }
        #pragma unroll
        for (int o = 32; o; o >>= 1) { s0 += __shfl_down(s0, o); s1 += __shfl_down(s1, o); }
        if (lane == 0) {
            s_alog[r0]     = s0 + attn_b[r0];
            s_alog[r0 + 1] = s1 + attn_b[r0 + 1];
        }
    }
    __syncthreads();

    // softmax (each thread redundantly)
    float mx = -INFINITY;
    #pragma unroll 4
    for (int l = 0; l < L_ENC; ++l) mx = fmaxf(mx, s_alog[l]);
    __syncthreads();
    if (t < L_ENC) s_alog[t] = expf(s_alog[t] - mx);
    __syncthreads();
    float ssum = 0.f;
    #pragma unroll 4
    for (int l = 0; l < L_ENC; ++l) ssum += s_alog[l];
    const float inv = 1.f / ssum;

    // ctx: thread t owns float4 column t
    const float4* enc4 = (const float4*)enc;   // [128][256]
    float4 c = make_float4(0.f, 0.f, 0.f, 0.f);
    #pragma unroll 4
    for (int l = 0; l < L_ENC; ++l) {
        float a = s_alog[l];
        float4 e = enc4[l * 256 + t];
        c.x += a * e.x; c.y += a * e.y; c.z += a * e.z; c.w += a * e.w;
    }
    cat4[256 + t] = make_float4(c.x * inv, c.y * inv, c.z * inv, c.w * inv);
    __syncthreads();

    // comb: 16 rows/block, 4/wave, batch 2
    for (int it = 0; it < 2; ++it) {
        const int r0 = blockIdx.x * 16 + wave * 4 + it * 2;   // 0..1023
        const float4* wc = (const float4*)(comb_w + (size_t)r0 * 2048);
        float4 a0[8], a1[8];
        #pragma unroll
        for (int m = 0; m < 8; ++m) a0[m] = wc[lane + (m << 6)];
        #pragma unroll
        for (int m = 0; m < 8; ++m) a1[m] = wc[512 + lane + (m << 6)];
        float s0 = 0.f, s1 = 0.f;
        #pragma unroll
        for (int m = 0; m < 8; ++m) {
            float4 b = cat4[lane + (m << 6)];
            s0 += a0[m].x * b.x + a0[m].y * b.y + a0[m].z * b.z + a0[m].w * b.w;
            s1 += a1[m].x * b.x + a1[m].y * b.y + a1[m].z * b.z + a1[m].w * b.w;
        }
        #pragma unroll
        for (int o = 32; o; o >>= 1) { s0 += __shfl_down(s0, o); s1 += __shfl_down(s1, o); }
        if (lane == 0) {
            ws[WS_X + r0]     = fmaxf(s0 + comb_b[r0], 0.f);
            ws[WS_X + r0 + 1] = fmaxf(s1 + comb_b[r0 + 1], 0.f);
        }
    }
}

// K_B: 256 blocks * 4 rows: all 3 gate dots batched + gate math -> h_new
__global__ __launch_bounds__(256) void k_gru(const float* __restrict__ wih,
                                             const float* __restrict__ bih,
                                             float* __restrict__ ws) {
    __shared__ __align__(16) float s_x[H];
    const int t = threadIdx.x, wave = t >> 6, lane = t & 63;
    for (int j = t; j < H; j += 256) s_x[j] = ws[WS_X + j];
    __syncthreads();
    const float4* x4 = (const float4*)s_x;
    const int i = blockIdx.x * 4 + wave;                // 0..1023
    const float4* w0 = (const float4*)(wih + (size_t)i * H);
    const float4* w1 = (const float4*)(wih + (size_t)(i + H) * H);
    const float4* w2 = (const float4*)(wih + (size_t)(i + 2 * H) * H);
    float4 a0[4], a1[4], a2[4];
    #pragma unroll
    for (int m = 0; m < 4; ++m) a0[m] = w0[lane + (m << 6)];
    #pragma unroll
    for (int m = 0; m < 4; ++m) a1[m] = w1[lane + (m << 6)];
    #pragma unroll
    for (int m = 0; m < 4; ++m) a2[m] = w2[lane + (m << 6)];
    float s0 = 0.f, s1 = 0.f, s2 = 0.f;
    #pragma unroll
    for (int m = 0; m < 4; ++m) {
        float4 b = x4[lane + (m << 6)];
        s0 += a0[m].x * b.x + a0[m].y * b.y + a0[m].z * b.z + a0[m].w * b.w;
        s1 += a1[m].x * b.x + a1[m].y * b.y + a1[m].z * b.z + a1[m].w * b.w;
        s2 += a2[m].x * b.x + a2[m].y * b.y + a2[m].z * b.z + a2[m].w * b.w;
    }
    #pragma unroll
    for (int o = 32; o; o >>= 1) {
        s0 += __shfl_down(s0, o); s1 += __shfl_down(s1, o); s2 += __shfl_down(s2, o);
    }
    if (lane == 0) {
        float gr = s0 + bih[i]         + ws[WS_GH + i];
        float gz = s1 + bih[i + H]     + ws[WS_GH + i + H];
        float gn = s2 + bih[i + 2*H];
        float r = 1.f / (1.f + expf(-gr));
        float z = 1.f / (1.f + expf(-gz));
        float n = tanhf(gn + r * ws[WS_GH + i + 2*H]);
        ws[WS_HNEW + i] = (1.f - z) * n + z * ws[WS_H + i];
    }
}

// K_C: 629 blocks * 80 rows: logits + per-block argmax; last block reduces
// and updates state (last-block trick, device-scope fence + atomic)
__global__ __launch_bounds__(256) void k_logits(const float* __restrict__ out_w,
                                                const float* __restrict__ out_b,
                                                float* __restrict__ ws,
                                                int* __restrict__ out, int step) {
    __shared__ __align__(16) float s_h[H];
    __shared__ float s_bv[4];
    __shared__ int   s_bi[4];
    __shared__ int   s_last;
    __shared__ float s_rv[256];
    __shared__ int   s_ri[256];
    const int t = threadIdx.x, wave = t >> 6, lane = t & 63;
    for (int j = t; j < H; j += 256) s_h[j] = ws[WS_HNEW + j];
    __syncthreads();
    const float4* h4 = (const float4*)s_h;

    const int rbase = blockIdx.x * ROWS_PB + wave * 20;
    float bv = -INFINITY; int bi = 0x7fffffff;
    for (int it = 0; it < 5; ++it) {
        const int r = rbase + it * 4;
        float4 a[4][4];
        #pragma unroll
        for (int q = 0; q < 4; ++q) {
            const int rq = min(r + q, V - 1);
            const float4* w4 = (const float4*)(out_w + (size_t)rq * H);
            #pragma unroll
            for (int m = 0; m < 4; ++m) a[q][m] = w4[lane + (m << 6)];
        }
        float s[4] = {0.f, 0.f, 0.f, 0.f};
        #pragma unroll
        for (int m = 0; m < 4; ++m) {
            float4 b = h4[lane + (m << 6)];
            #pragma unroll
            for (int q = 0; q < 4; ++q)
                s[q] += a[q][m].x * b.x + a[q][m].y * b.y + a[q][m].z * b.z + a[q][m].w * b.w;
        }
        #pragma unroll
        for (int o = 32; o; o >>= 1) {
            #pragma unroll
            for (int q = 0; q < 4; ++q) s[q] += __shfl_xor(s[q], o);
        }
        #pragma unroll
        for (int q = 0; q < 4; ++q) {
            const int rq = r + q;
            if (rq < V) {
                float v = s[q] + out_b[rq];
                if (v > bv) { bv = v; bi = rq; }   // ascending scan keeps first max
            }
        }
    }
    if (lane == 0) { s_bv[wave] = bv; s_bi[wave] = bi; }
    __syncthreads();
    if (t == 0) {
        for (int w2 = 1; w2 < 4; ++w2) {
            float v = s_bv[w2]; int i2 = s_bi[w2];
            if (v > bv || (v == bv && i2 < bi)) { bv = v; bi = i2; }
        }
        ws[WS_PMAX + blockIdx.x] = bv;
        ((int*)(ws + WS_PIDX))[blockIdx.x] = bi;
        __threadfence();                           // publish partial (device scope)
        unsigned prev = atomicAdd((unsigned*)(ws + WS_CNT), 1u);
        s_last = (prev == NB_OUT - 1);
    }
    __syncthreads();
    if (!s_last) return;

    // ---- last block: global argmax + state update ----
    __threadfence();                               // acquire all partials
    volatile float* pv = ws + WS_PMAX;
    volatile int*   pi = (int*)(ws + WS_PIDX);
    float rv = -INFINITY; int ri = 0x7fffffff;
    for (int e = t; e < NB_OUT; e += 256) {        // ascending -> first-max kept
        float v = pv[e]; int i2 = pi[e];
        if (v > rv || (v == rv && i2 < ri)) { rv = v; ri = i2; }
    }
    s_rv[t] = rv; s_ri[t] = ri;
    __syncthreads();
    #pragma unroll
    for (int o = 128; o; o >>= 1) {
        if (t < o) {
            float v2 = s_rv[t + o]; int i2 = s_ri[t + o];
            if (v2 > s_rv[t] || (v2 == s_rv[t] && i2 < s_ri[t])) { s_rv[t] = v2; s_ri[t] = i2; }
        }
        __syncthreads();
    }
    const int top = s_ri[0];
    const int done_old = ((const int*)(ws + WS_DONE))[0];
    if (!done_old) {                               // h_next uses OLD done
        for (int j = t; j < H; j += 256) ws[WS_H + j] = ws[WS_HNEW + j];
    }
    if (t == 0) {
        out[step] = done_old ? 0 : top;
        ((int*)(ws + WS_TOK))[0]  = top;
        ((int*)(ws + WS_DONE))[0] = done_old | (top == 1) | (top == STOP_ID);
        ((unsigned*)(ws + WS_CNT))[0] = 0;         // re-arm for next step
    }
}

extern "C" void kernel_launch(void* const* d_in, const int* in_sizes, int n_in,
                              void* d_out, int out_size, void* d_ws, size_t ws_size,
                              hipStream_t stream) {
    const int*   dec_in = (const int*)  d_in[0];
    const float* h0     = (const float*)d_in[1];
    const float* enc    = (const float*)d_in[2];
    const float* emb    = (const float*)d_in[3];
    const float* attn_w = (const float*)d_in[4];
    const float* attn_b = (const float*)d_in[5];
    const float* comb_w = (const float*)d_in[6];
    const float* comb_b = (const float*)d_in[7];
    const float* wih    = (const float*)d_in[8];
    const float* whh    = (const float*)d_in[9];
    const float* bih    = (const float*)d_in[10];
    const float* bhh    = (const float*)d_in[11];
    const float* out_w  = (const float*)d_in[12];
    const float* out_b  = (const float*)d_in[13];
    float* ws = (float*)d_ws;
    int*   out = (int*)d_out;

    k_init<<<1, 1024, 0, stream>>>(dec_in, h0, ws);
    for (int step = 0; step < STEPS; ++step) {
        k_A<<<832, 256, 0, stream>>>(emb, attn_w, attn_b, enc, comb_w, comb_b, whh, bhh, ws);
        k_gru<<<256, 256, 0, stream>>>(wih, bih, ws);
        k_logits<<<NB_OUT, 256, 0, stream>>>(out_w, out_b, ws, out, step);
    }
}